// Round 10
// baseline (195.952 us; speedup 1.0000x reference)
//
#include <hip/hip_runtime.h>
#include <stdint.h>

// CSSA: B=32, H=W=64, C=64, heads=4, hd=16, strip windows 64x8 -> 256 windows.
// Round 15: r14 structure (block=(window,head,q-half), 2048x512, 4 blocks/CU;
// r14 proved conflicts are TLP-hidden: 7.2M->2.6M bought 0 us). VALU-issue is
// the bound (63% busy = 47.7us floor at current op count) -> cut VALU ops:
//  1. Denominator via ones-MFMA: lsum[t]=mfma(ones,P,lsum) sums all 16 chunk
//     keys into every C row -> removes 4 adds/(c,t) (-256 VALU/wave) AND the
//     cross-quad shfl reduce. MFMA pipe at 18% has headroom. Denominator now
//     sums the SAME bf16 P as the numerator (error partially cancels).
//  2. Maskless epilogue: VSTR 520->552, rows zero-padded [0,16)+[528,552).
//     y-OOB taps read zeros (no &511, no clamp, no cndmask); x-wrap killed by
//     folding the 2 x-masks into weights once per j (6 vs 72 cndmask).
//  3. Cross-chunk kf/vf prefetch (LDS latency under prev chunk's MFMA+exp).
//  4. s_setprio(1) around each chunk's MFMA+exp cluster (T5; 4 independent
//     blocks/CU = phase diversity).
// Bank check VSTR=552 (276 dw == 20 mod 32): frag reads & staging writes land
// 4-way on even banks == r14's profile. LDS 38.8KB x4 = 155KB <= 160 OK.
// QK^T transposed (A=K,B=Q) so P's C-layout == K=16 B-frag layout: PV and
// ones-MFMA consume P straight from registers.
#define KSTR2 20    // K row: 16 ch + 4 pad (40 B)
#define VSTR  552   // Vt row: 16 zero | 512 tok | 24 zero

typedef __attribute__((ext_vector_type(4))) short          short4v;
typedef __attribute__((ext_vector_type(4))) float          f32x4;
typedef __attribute__((ext_vector_type(4))) unsigned short us4;
typedef __bf16 bf2_t __attribute__((ext_vector_type(2)));

__device__ __forceinline__ float bf2f(unsigned short u) {
    union { unsigned int i; float f; } x; x.i = ((unsigned int)u) << 16; return x.f;
}
__device__ __forceinline__ unsigned int pk2bf(float lo, float hi) {
#if __has_builtin(__builtin_amdgcn_cvt_pk_bf16_f32)
    union { bf2_t v; unsigned int u; } c;
    c.v = __builtin_amdgcn_cvt_pk_bf16_f32(lo, hi);     // 1 VALU op
    return c.u;
#else
    union { float f; unsigned int u; } a, b; a.f = lo; b.f = hi;
    return __builtin_amdgcn_perm(b.u + 0x8000u, a.u + 0x8000u, 0x07060302u);
#endif
}
__device__ __forceinline__ short4v pk4bf(float a, float b, float c, float d) {
    union { short4v s; unsigned int u[2]; } p;
    p.u[0] = pk2bf(a, b);
    p.u[1] = pk2bf(c, d);
    return p.s;
}

__global__ __launch_bounds__(512, 6)
void CSSA_69355131896243_kernel(const float* __restrict__ qkv,
                                const float* __restrict__ wconv,
                                const float* __restrict__ bconv,
                                float* __restrict__ out)
{
    __shared__ unsigned short Kl[512 * KSTR2];   // 20480 B  K[token][d] bf16
    __shared__ unsigned short Vt[16 * VSTR];     // 17664 B  V^T[d][pad|tok|pad]
    __shared__ float Wl[144];                    // head's 16x9 conv weights
    __shared__ float Bl[16];

    const int tid  = threadIdx.x;
    const int wave = tid >> 6, lane = tid & 63, quad = lane >> 4, l15 = lane & 15;

    // bid = x + 8*s + 64*y: s=(head,qh). s-siblings of a window adjacent in
    // dispatch -> same XCD -> shared K/V reads + output sectors merge in L2.
    const int bid  = blockIdx.x;
    const int x    = bid & 7, s = (bid >> 3) & 7, y = bid >> 6;
    const int head = s & 3, qh = s >> 2;
    const int win  = x * 32 + y;
    const int b    = win >> 3, wx = win & 7;
    const int hc   = head * 16;

    const size_t ONE  = (size_t)32 * 4096 * 64;
    const size_t base = ((size_t)b * 4096 + (size_t)wx * 8) * 64;
    const float* gQ = qkv + base;
    const float* gK = qkv + ONE + base;
    const float* gV = qkv + 2 * ONE + base;

    // ---- stage K rows: thread=(t0=tid>>2, c4=tid&3), 128 tokens/round ----
    {
        const int c4 = tid & 3;
        const int t0 = tid >> 2;
        #pragma unroll
        for (int r = 0; r < 4; ++r) {
            const int t = r * 128 + t0;
            const size_t goff = (size_t)(t >> 3) * 4096 + (size_t)(t & 7) * 64 + hc + c4 * 4;
            f32x4 kd = *(const f32x4*)(gK + goff);
            union { us4 v; unsigned int u[2]; } kb;
            kb.u[0] = pk2bf(kd[0], kd[1]);
            kb.u[1] = pk2bf(kd[2], kd[3]);
            *(us4*)(&Kl[t * KSTR2 + c4 * 4]) = kb.v;
        }
        // ---- stage V^T channel-major: lane=(d=tid&15, g=tid>>4 + 32r) ----
        const int d = tid & 15;
        #pragma unroll
        for (int r = 0; r < 4; ++r) {
            const int g = (tid >> 4) + r * 32;          // token group: t=g*4+i
            const float* src = gV + (size_t)(g >> 1) * 4096 + (size_t)((g & 1) * 4) * 64 + hc + d;
            const float v0 = src[0], v1 = src[64], v2 = src[128], v3 = src[192];
            union { us4 v; unsigned int u[2]; } vb;
            vb.u[0] = pk2bf(v0, v1);
            vb.u[1] = pk2bf(v2, v3);
            *(us4*)(&Vt[d * VSTR + 16 + g * 4]) = vb.v; // 4 consecutive tokens
        }
        // ---- zero the pads: 16 rows x (16 + 24) shorts = 160 us4 writes ----
        if (tid < 160) {
            const int row = tid / 10, seg = tid % 10;
            const int off = (seg < 4) ? seg * 4 : 528 + (seg - 4) * 4;
            *(us4*)(&Vt[row * VSTR + off]) = (us4){0, 0, 0, 0};
        }
    }
    if (tid < 144) Wl[tid] = wconv[head * 144 + tid];
    if (tid < 16)  Bl[tid] = bconv[hc + tid];

    // ---- Q prefetch + pack (independent of LDS -> overlaps barrier wait) ----
    const float SCL = 0.25f * 1.44269504088896341f;   // scale*log2(e) folded in
    const int q0 = qh * 256 + wave * 32;
    short4v qf[2];   // B[k=d=quad*4+i][n=q=l15]
    #pragma unroll
    for (int t = 0; t < 2; ++t) {
        const int q = q0 + t * 16 + l15;
        f32x4 qv = *(const f32x4*)(gQ + (size_t)(q >> 3) * 4096 + (size_t)(q & 7) * 64 + hc + quad * 4);
        qf[t] = pk4bf(qv[0] * SCL, qv[1] * SCL, qv[2] * SCL, qv[3] * SCL);
    }
    __syncthreads();

    f32x4 acc[2], lsum[2];
    #pragma unroll
    for (int t = 0; t < 2; ++t) { acc[t] = (f32x4)0.0f; lsum[t] = (f32x4)0.0f; }
    const short4v ones = {(short)0x3F80, (short)0x3F80, (short)0x3F80, (short)0x3F80};

    // ---- main loop: 32 chunks x 16 keys, cross-chunk prefetch, setprio ----
    const unsigned short* Kbase = &Kl[l15 * KSTR2 + quad * 4];       // +c*320
    const unsigned short* Vbase = &Vt[l15 * VSTR + 16 + quad * 4];   // +c*16
    short4v kf = *(const short4v*)(Kbase);
    short4v vf = *(const short4v*)(Vbase);
    #pragma unroll 4
    for (int c = 0; c < 32; ++c) {
        const int cn = (c + 1) & 31;                   // wrap: dead read at 31
        const short4v kfn = *(const short4v*)(Kbase + cn * 320);
        const short4v vfn = *(const short4v*)(Vbase + cn * 16);
        __builtin_amdgcn_s_setprio(1);
        #pragma unroll
        for (int t = 0; t < 2; ++t) {
            // s^T[key][q]: C row=quad*4+j -> key, col=l15 -> q
            f32x4 sc = __builtin_amdgcn_mfma_f32_16x16x16bf16_1k(kf, qf[t], (f32x4)0.0f, 0, 0, 0);
            const float p0 = __builtin_amdgcn_exp2f(sc[0]);
            const float p1 = __builtin_amdgcn_exp2f(sc[1]);
            const float p2 = __builtin_amdgcn_exp2f(sc[2]);
            const float p3 = __builtin_amdgcn_exp2f(sc[3]);
            // P C-layout == K=16 B-frag layout -> PV straight from registers
            const short4v pb = pk4bf(p0, p1, p2, p3);
            lsum[t] = __builtin_amdgcn_mfma_f32_16x16x16bf16_1k(ones, pb, lsum[t], 0, 0, 0);
            acc[t]  = __builtin_amdgcn_mfma_f32_16x16x16bf16_1k(vf,   pb, acc[t],  0, 0, 0);
        }
        __builtin_amdgcn_s_setprio(0);
        kf = kfn; vf = vfn;
    }

    // ---- denominators: ones-MFMA already summed all 512 keys per q ----
    float linv[2];
    #pragma unroll
    for (int t = 0; t < 2; ++t) linv[t] = __builtin_amdgcn_rcpf(lsum[t][0]);

    // ---- epilogue: maskless LePE from zero-padded V^T rows, store ----
    const int xx0 = l15 & 7;            // x = q&7, t-invariant
    const bool mx0 = (xx0 >= 1), mx2 = (xx0 <= 6);
    #pragma unroll
    for (int j = 0; j < 4; ++j) {
        const int d = quad * 4 + j;
        float w9[9];
        #pragma unroll
        for (int o = 0; o < 9; ++o) w9[o] = Wl[d * 9 + o];
        // fold x-masks into weights: dx=0 cols need x>=1, dx=2 cols need x<=6
        w9[0] = mx0 ? w9[0] : 0.0f;  w9[3] = mx0 ? w9[3] : 0.0f;  w9[6] = mx0 ? w9[6] : 0.0f;
        w9[2] = mx2 ? w9[2] : 0.0f;  w9[5] = mx2 ? w9[5] : 0.0f;  w9[8] = mx2 ? w9[8] : 0.0f;
        const float bs = Bl[d];
        const unsigned short* vrow = &Vt[d * VSTR + 16];
        #pragma unroll
        for (int t = 0; t < 2; ++t) {
            const int q = q0 + t * 16 + l15;
            float lep = bs;
            #pragma unroll
            for (int dy = 0; dy < 3; ++dy) {
                #pragma unroll
                for (int dx = 0; dx < 3; ++dx) {
                    // y-OOB indices land in the zeroed pads: no mask needed
                    lep += w9[dy * 3 + dx] * bf2f(vrow[q + (dy - 1) * 8 + (dx - 1)]);
                }
            }
            acc[t][j] = acc[t][j] * linv[t] + lep;
        }
    }
    float* gO = out + base;
    #pragma unroll
    for (int t = 0; t < 2; ++t) {
        const int q = q0 + t * 16 + l15;
        *(f32x4*)(gO + (size_t)(q >> 3) * 4096 + (size_t)(q & 7) * 64 + hc + quad * 4) = acc[t];
    }
}

extern "C" void kernel_launch(void* const* d_in, const int* in_sizes, int n_in,
                              void* d_out, int out_size, void* d_ws, size_t ws_size,
                              hipStream_t stream) {
    const float* qkv   = (const float*)d_in[0];
    const float* wconv = (const float*)d_in[1];
    const float* bconv = (const float*)d_in[2];
    float* outp = (float*)d_out;
    hipLaunchKernelGGL(CSSA_69355131896243_kernel, dim3(2048), dim3(512), 0, stream,
                       qkv, wconv, bconv, outp);
}

// Round 12
// 186.173 us; speedup vs baseline: 1.0525x; 1.0525x over previous
//
#include <hip/hip_runtime.h>
#include <stdint.h>

// CSSA: B=32, H=W=64, C=64, heads=4, hd=16, strip windows 64x8 -> 256 windows.
// Round 16 RESUBMIT (r11 bench died to infra: "container failed twice", same
// as r4 which ran clean on resubmit; kernel audited: LDS 38.8KB, tap ranges
// in-bounds, no divergent barriers).
// r14 base (75.7us; block=(window,head,q-half), 2048x512, 4 blk/CU).
// r15 post-mortem: VALU cut landed (63->47%) but dur ROSE 7us -> latency-bound
// on the per-chunk serial chain, not issue-bound. ones-MFMA lengthened the
// chain + lockstep setprio hurt (m190). This round:
//  1. Explicit 2-way chunk interleave (c, c+16; acc[t][half] merged at end):
//     4 independent QK->exp2->pack->PV chains in flight (was 2) -> covers
//     MFMA+exp2 latency with real ILP. ~+12 VGPR (est ~55; <=64 keeps 8 w/SIMD).
//  2. Maskless epilogue, isolated from r15's bad bundle: VSTR 520->552 with
//     zeroed pads (y-OOB taps read 0; x-masks folded into weights: 6 vs 72
//     cndmask). Pure -140 VALU ops/thread, no chain impact.
//  3. NO ones-MFMA, NO setprio, NO prefetch rotation (r14 imm-offset reads).
// Bank check VSTR=552 (276 dw == 20 mod 32): frag reads l15*20 mod 32 covers
// 8 even slots x2 lanes x4 quads ~= 4/bank (same as r14's 260==4); epilogue
// taps consecutive-token = free. LDS 38.8KB x4 = 155.4 <= 160 OK.
// QK^T transposed (A=K,B=Q) so P's C-layout == K=16 B-frag layout: PV MFMA
// consumes P straight from registers.
#define KSTR2 20    // K row: 16 ch + 4 pad (40 B)
#define VSTR  552   // Vt row: 16 zero | 512 tok | 24 zero

typedef __attribute__((ext_vector_type(4))) short          short4v;
typedef __attribute__((ext_vector_type(4))) float          f32x4;
typedef __attribute__((ext_vector_type(4))) unsigned short us4;
typedef __bf16 bf2_t __attribute__((ext_vector_type(2)));

__device__ __forceinline__ float bf2f(unsigned short u) {
    union { unsigned int i; float f; } x; x.i = ((unsigned int)u) << 16; return x.f;
}
__device__ __forceinline__ unsigned int pk2bf(float lo, float hi) {
#if __has_builtin(__builtin_amdgcn_cvt_pk_bf16_f32)
    union { bf2_t v; unsigned int u; } c;
    c.v = __builtin_amdgcn_cvt_pk_bf16_f32(lo, hi);     // 1 VALU op
    return c.u;
#else
    union { float f; unsigned int u; } a, b; a.f = lo; b.f = hi;
    return __builtin_amdgcn_perm(b.u + 0x8000u, a.u + 0x8000u, 0x07060302u);
#endif
}
__device__ __forceinline__ short4v pk4bf(float a, float b, float c, float d) {
    union { short4v s; unsigned int u[2]; } p;
    p.u[0] = pk2bf(a, b);
    p.u[1] = pk2bf(c, d);
    return p.s;
}

__global__ __launch_bounds__(512, 6)
void CSSA_69355131896243_kernel(const float* __restrict__ qkv,
                                const float* __restrict__ wconv,
                                const float* __restrict__ bconv,
                                float* __restrict__ out)
{
    __shared__ unsigned short Kl[512 * KSTR2];   // 20480 B  K[token][d] bf16
    __shared__ unsigned short Vt[16 * VSTR];     // 17664 B  V^T[d][pad|tok|pad]
    __shared__ float Wl[144];                    // head's 16x9 conv weights
    __shared__ float Bl[16];

    const int tid  = threadIdx.x;
    const int wave = tid >> 6, lane = tid & 63, quad = lane >> 4, l15 = lane & 15;

    // bid = x + 8*s + 64*y: s=(head,qh). s-siblings of a window adjacent in
    // dispatch -> same XCD -> shared K/V reads + output sectors merge in L2.
    const int bid  = blockIdx.x;
    const int x    = bid & 7, s = (bid >> 3) & 7, y = bid >> 6;
    const int head = s & 3, qh = s >> 2;
    const int win  = x * 32 + y;
    const int b    = win >> 3, wx = win & 7;
    const int hc   = head * 16;

    const size_t ONE  = (size_t)32 * 4096 * 64;
    const size_t base = ((size_t)b * 4096 + (size_t)wx * 8) * 64;
    const float* gQ = qkv + base;
    const float* gK = qkv + ONE + base;
    const float* gV = qkv + 2 * ONE + base;

    // ---- stage K rows: thread=(t0=tid>>2, c4=tid&3), 128 tokens/round ----
    {
        const int c4 = tid & 3;
        const int t0 = tid >> 2;
        #pragma unroll
        for (int r = 0; r < 4; ++r) {
            const int t = r * 128 + t0;
            const size_t goff = (size_t)(t >> 3) * 4096 + (size_t)(t & 7) * 64 + hc + c4 * 4;
            f32x4 kd = *(const f32x4*)(gK + goff);
            union { us4 v; unsigned int u[2]; } kb;
            kb.u[0] = pk2bf(kd[0], kd[1]);
            kb.u[1] = pk2bf(kd[2], kd[3]);
            *(us4*)(&Kl[t * KSTR2 + c4 * 4]) = kb.v;
        }
        // ---- stage V^T channel-major: lane=(d=tid&15, g=tid>>4 + 32r) ----
        const int d = tid & 15;
        #pragma unroll
        for (int r = 0; r < 4; ++r) {
            const int g = (tid >> 4) + r * 32;          // token group: t=g*4+i
            const float* src = gV + (size_t)(g >> 1) * 4096 + (size_t)((g & 1) * 4) * 64 + hc + d;
            const float v0 = src[0], v1 = src[64], v2 = src[128], v3 = src[192];
            union { us4 v; unsigned int u[2]; } vb;
            vb.u[0] = pk2bf(v0, v1);
            vb.u[1] = pk2bf(v2, v3);
            *(us4*)(&Vt[d * VSTR + 16 + g * 4]) = vb.v; // 4 consecutive tokens
        }
        // ---- zero the pads: 16 rows x (16 + 24) shorts = 160 us4 writes ----
        if (tid < 160) {
            const int row = tid / 10, seg = tid % 10;
            const int off = (seg < 4) ? seg * 4 : 528 + (seg - 4) * 4;
            *(us4*)(&Vt[row * VSTR + off]) = (us4){0, 0, 0, 0};
        }
    }
    if (tid < 144) Wl[tid] = wconv[head * 144 + tid];
    if (tid < 16)  Bl[tid] = bconv[hc + tid];

    // ---- Q prefetch + pack (independent of LDS -> overlaps barrier wait) ----
    const float SCL = 0.25f * 1.44269504088896341f;   // scale*log2(e) folded in
    const int q0 = qh * 256 + wave * 32;
    short4v qf[2];   // B[k=d=quad*4+i][n=q=l15]
    #pragma unroll
    for (int t = 0; t < 2; ++t) {
        const int q = q0 + t * 16 + l15;
        f32x4 qv = *(const f32x4*)(gQ + (size_t)(q >> 3) * 4096 + (size_t)(q & 7) * 64 + hc + quad * 4);
        qf[t] = pk4bf(qv[0] * SCL, qv[1] * SCL, qv[2] * SCL, qv[3] * SCL);
    }
    __syncthreads();

    f32x4 acc[2][2];     // [t][half]
    float lp[2];
    #pragma unroll
    for (int t = 0; t < 2; ++t) {
        acc[t][0] = (f32x4)0.0f; acc[t][1] = (f32x4)0.0f; lp[t] = 0.0f;
    }

    // ---- main loop: 16 iters x 2 interleaved chunks (c, c+16) x 16 keys ----
    const unsigned short* Kb = &Kl[l15 * KSTR2 + quad * 4];       // +c*320
    const unsigned short* Vb = &Vt[l15 * VSTR + 16 + quad * 4];   // +c*16
    #pragma unroll 2
    for (int c = 0; c < 16; ++c) {
        // K A-frags: A[m=key=l15][k=d=quad*4+i]; V A-frags: A[m=d=l15][k=key]
        const short4v kfA = *(const short4v*)(Kb + c * 320);
        const short4v kfB = *(const short4v*)(Kb + (c + 16) * 320);
        const short4v vfA = *(const short4v*)(Vb + c * 16);
        const short4v vfB = *(const short4v*)(Vb + (c + 16) * 16);
        #pragma unroll
        for (int t = 0; t < 2; ++t) {
            // s^T[key][q]: C row=quad*4+j -> key, col=l15 -> q
            f32x4 sA = __builtin_amdgcn_mfma_f32_16x16x16bf16_1k(kfA, qf[t], (f32x4)0.0f, 0, 0, 0);
            f32x4 sB = __builtin_amdgcn_mfma_f32_16x16x16bf16_1k(kfB, qf[t], (f32x4)0.0f, 0, 0, 0);
            const float a0 = __builtin_amdgcn_exp2f(sA[0]);
            const float a1 = __builtin_amdgcn_exp2f(sA[1]);
            const float a2 = __builtin_amdgcn_exp2f(sA[2]);
            const float a3 = __builtin_amdgcn_exp2f(sA[3]);
            const float b0 = __builtin_amdgcn_exp2f(sB[0]);
            const float b1 = __builtin_amdgcn_exp2f(sB[1]);
            const float b2 = __builtin_amdgcn_exp2f(sB[2]);
            const float b3 = __builtin_amdgcn_exp2f(sB[3]);
            lp[t] += ((a0 + a1) + (a2 + a3)) + ((b0 + b1) + (b2 + b3));
            // P C-layout == K=16 B-frag layout -> PV straight from registers
            acc[t][0] = __builtin_amdgcn_mfma_f32_16x16x16bf16_1k(vfA, pk4bf(a0, a1, a2, a3), acc[t][0], 0, 0, 0);
            acc[t][1] = __builtin_amdgcn_mfma_f32_16x16x16bf16_1k(vfB, pk4bf(b0, b1, b2, b3), acc[t][1], 0, 0, 0);
        }
    }

    // ---- merge halves + denominators: cross-quad reduce ----
    f32x4 accm[2];
    float linv[2];
    #pragma unroll
    for (int t = 0; t < 2; ++t) {
        accm[t] = acc[t][0] + acc[t][1];
        float v = lp[t];
        v += __shfl_xor(v, 16, 64);
        v += __shfl_xor(v, 32, 64);
        linv[t] = __builtin_amdgcn_rcpf(v);
    }

    // ---- epilogue: maskless LePE from zero-padded V^T rows, store ----
    const int xx0 = l15 & 7;            // x = q&7, t-invariant
    const bool mx0 = (xx0 >= 1), mx2 = (xx0 <= 6);
    #pragma unroll
    for (int j = 0; j < 4; ++j) {
        const int d = quad * 4 + j;
        float w9[9];
        #pragma unroll
        for (int o = 0; o < 9; ++o) w9[o] = Wl[d * 9 + o];
        // fold x-masks into weights: dx=0 cols need x>=1, dx=2 cols need x<=6
        w9[0] = mx0 ? w9[0] : 0.0f;  w9[3] = mx0 ? w9[3] : 0.0f;  w9[6] = mx0 ? w9[6] : 0.0f;
        w9[2] = mx2 ? w9[2] : 0.0f;  w9[5] = mx2 ? w9[5] : 0.0f;  w9[8] = mx2 ? w9[8] : 0.0f;
        const float bs = Bl[d];
        const unsigned short* vrow = &Vt[d * VSTR + 16];
        #pragma unroll
        for (int t = 0; t < 2; ++t) {
            const int q = q0 + t * 16 + l15;
            float lep = bs;
            #pragma unroll
            for (int dy = 0; dy < 3; ++dy) {
                #pragma unroll
                for (int dx = 0; dx < 3; ++dx) {
                    // y-OOB indices land in the zeroed pads: no mask needed
                    lep += w9[dy * 3 + dx] * bf2f(vrow[q + (dy - 1) * 8 + (dx - 1)]);
                }
            }
            accm[t][j] = accm[t][j] * linv[t] + lep;
        }
    }
    float* gO = out + base;
    #pragma unroll
    for (int t = 0; t < 2; ++t) {
        const int q = q0 + t * 16 + l15;
        *(f32x4*)(gO + (size_t)(q >> 3) * 4096 + (size_t)(q & 7) * 64 + hc + quad * 4) = accm[t];
    }
}

extern "C" void kernel_launch(void* const* d_in, const int* in_sizes, int n_in,
                              void* d_out, int out_size, void* d_ws, size_t ws_size,
                              hipStream_t stream) {
    const float* qkv   = (const float*)d_in[0];
    const float* wconv = (const float*)d_in[1];
    const float* bconv = (const float*)d_in[2];
    float* outp = (float*)d_out;
    hipLaunchKernelGGL(CSSA_69355131896243_kernel, dim3(2048), dim3(512), 0, stream,
                       qkv, wconv, bconv, outp);
}